// Round 1
// baseline (902.106 us; speedup 1.0000x reference)
//
#include <hip/hip_runtime.h>
#include <hip/hip_bf16.h>

// Problem constants (fixed by reference setup_inputs)
#define B_ROWS 8192
#define D_DIM  768

// Tile config: 128x128 block tile, K-step 32, 512 threads = 8 waves (2x4),
// each wave owns a 64x32 output sub-tile = 4x2 fragments of 16x16.
#define BM 128
#define BN 128
#define BK 32
#define NTHREADS 512

typedef __attribute__((ext_vector_type(8))) short bf16x8;           // MFMA A/B frag (8 bf16)
typedef __attribute__((ext_vector_type(8))) unsigned short u16x8;   // LDS store vector
typedef __attribute__((ext_vector_type(4))) float f32x4;            // MFMA C/D frag

__device__ __forceinline__ unsigned short f2bf(float x) {
  // round-to-nearest-even fp32 -> bf16 (inputs are finite; no NaN handling)
  unsigned int u = __float_as_uint(x);
  u += 0x7fffu + ((u >> 16) & 1u);
  return (unsigned short)(u >> 16);
}

__device__ __forceinline__ float4 f4mul(float4 a, float4 b) {
  return make_float4(a.x * b.x, a.y * b.y, a.z * b.z, a.w * b.w);
}

__device__ __forceinline__ u16x8 cvt8(float4 a, float4 b) {
  u16x8 v;
  v[0] = f2bf(a.x); v[1] = f2bf(a.y); v[2] = f2bf(a.z); v[3] = f2bf(a.w);
  v[4] = f2bf(b.x); v[5] = f2bf(b.y); v[6] = f2bf(b.z); v[7] = f2bf(b.w);
  return v;
}

// Kernel 1: n_i = max(||f_i * m_i||, eps) in fp32; also zero the output scalar.
__global__ __launch_bounds__(256) void rownorm_zero_kernel(
    const float* __restrict__ f, const float* __restrict__ mask,
    float* __restrict__ n_i, float* __restrict__ out) {
  if (blockIdx.x == 0 && threadIdx.x == 0) out[0] = 0.0f;
  const int wv = threadIdx.x >> 6;
  const int lane = threadIdx.x & 63;
  const int row = blockIdx.x * 4 + wv;
  const float* fr = f + (size_t)row * D_DIM;
  const float* mr = mask + (size_t)row * D_DIM;
  float s = 0.f;
  for (int d = lane; d < D_DIM; d += 64) {
    float v = fr[d] * mr[d];
    s += v * v;
  }
  for (int off = 32; off > 0; off >>= 1) s += __shfl_down(s, off);
  if (lane == 0) n_i[row] = fmaxf(sqrtf(s), 1e-12f);
}

// Kernel 2: fused triple-GEMM + pointwise loss + reduction.
//  accS = f_i . f_j          (teacher sim)
//  accN = (f_i*m2_i) . f_j   (student numerator)
//  accD = m2_i . f_j^2       (student denom^2 term)
__global__ __launch_bounds__(NTHREADS, 2) void fused_loss_kernel(
    const float* __restrict__ f, const float* __restrict__ mask,
    const float* __restrict__ n_i, float* __restrict__ out) {
  __shared__ unsigned short sF[BM][BK];    // bf16(f_i)
  __shared__ unsigned short sFM2[BM][BK];  // bf16(f_i * m2_i)
  __shared__ unsigned short sM2[BM][BK];   // bf16(m2_i)
  __shared__ unsigned short sBF[BN][BK];   // bf16(f_j)
  __shared__ unsigned short sBF2[BN][BK];  // bf16(f_j^2)
  __shared__ float red[8];

  const int t    = threadIdx.x;
  const int lane = t & 63;
  const int wv   = t >> 6;        // wave id 0..7
  const int wm   = wv >> 2;       // 0..1  (row group of 64)
  const int wn   = wv & 3;        // 0..3  (col group of 32)
  const int frg  = lane & 15;     // fragment row
  const int ko   = (lane >> 4) * 8;  // fragment k offset

  const int i0 = blockIdx.y * BM;
  const int j0 = blockIdx.x * BN;

  // staging decomposition: each thread handles 8 contiguous elements of a
  // 128x32 tile (4096 elems / 512 threads)
  const int ar = t >> 2;          // row 0..127
  const int ac = (t & 3) * 8;     // col 0,8,16,24

  f32x4 accS[4][2], accN[4][2], accD[4][2];
  for (int m = 0; m < 4; ++m)
    for (int n = 0; n < 2; ++n) {
      accS[m][n] = {0.f, 0.f, 0.f, 0.f};
      accN[m][n] = {0.f, 0.f, 0.f, 0.f};
      accD[m][n] = {0.f, 0.f, 0.f, 0.f};
    }

  const float* fA = f    + (size_t)(i0 + ar) * D_DIM + ac;
  const float* mA = mask + (size_t)(i0 + ar) * D_DIM + ac;
  const float* fB = f    + (size_t)(j0 + ar) * D_DIM + ac;

  for (int k0 = 0; k0 < D_DIM; k0 += BK) {
    __syncthreads();  // protect LDS from previous iteration's readers
    // ---- stage: fp32 global -> bf16 LDS (reg-staged conversion) ----
    float4 fa0 = *(const float4*)(fA + k0);
    float4 fa1 = *(const float4*)(fA + k0 + 4);
    float4 ma0 = *(const float4*)(mA + k0);
    float4 ma1 = *(const float4*)(mA + k0 + 4);
    float4 fb0 = *(const float4*)(fB + k0);
    float4 fb1 = *(const float4*)(fB + k0 + 4);
    float4 m20 = f4mul(ma0, ma0), m21 = f4mul(ma1, ma1);
    float4 fm0 = f4mul(fa0, m20), fm1 = f4mul(fa1, m21);
    float4 f20 = f4mul(fb0, fb0), f21 = f4mul(fb1, fb1);
    *(u16x8*)&sF[ar][ac]   = cvt8(fa0, fa1);
    *(u16x8*)&sFM2[ar][ac] = cvt8(fm0, fm1);
    *(u16x8*)&sM2[ar][ac]  = cvt8(m20, m21);
    *(u16x8*)&sBF[ar][ac]  = cvt8(fb0, fb1);
    *(u16x8*)&sBF2[ar][ac] = cvt8(f20, f21);
    __syncthreads();
    // ---- compute: 24 MFMAs per wave per K-step ----
    bf16x8 bF[2], bF2[2];
    for (int n = 0; n < 2; ++n) {
      bF[n]  = *(const bf16x8*)&sBF [wn * 32 + n * 16 + frg][ko];
      bF2[n] = *(const bf16x8*)&sBF2[wn * 32 + n * 16 + frg][ko];
    }
#pragma unroll
    for (int m = 0; m < 4; ++m) {
      bf16x8 aF = *(const bf16x8*)&sF  [wm * 64 + m * 16 + frg][ko];
      bf16x8 aN = *(const bf16x8*)&sFM2[wm * 64 + m * 16 + frg][ko];
      bf16x8 aD = *(const bf16x8*)&sM2 [wm * 64 + m * 16 + frg][ko];
#pragma unroll
      for (int n = 0; n < 2; ++n) {
        accS[m][n] = __builtin_amdgcn_mfma_f32_16x16x32_bf16(aF, bF[n],  accS[m][n], 0, 0, 0);
        accN[m][n] = __builtin_amdgcn_mfma_f32_16x16x32_bf16(aN, bF[n],  accN[m][n], 0, 0, 0);
        accD[m][n] = __builtin_amdgcn_mfma_f32_16x16x32_bf16(aD, bF2[n], accD[m][n], 0, 0, 0);
      }
    }
  }

  // ---- epilogue: pointwise loss + off-diagonal masked reduction ----
  // C/D layout (m89-verified): col = lane&15, row = (lane>>4)*4 + reg
  float sum = 0.f;
  const int r4 = (lane >> 4) * 4;
  const int cc = lane & 15;
#pragma unroll
  for (int m = 0; m < 4; ++m) {
    const int gi_base = i0 + wm * 64 + m * 16 + r4;
#pragma unroll
    for (int jj = 0; jj < 4; ++jj) {
      const int gi = gi_base + jj;
      const float ni = n_i[gi];
#pragma unroll
      for (int n = 0; n < 2; ++n) {
        const int gj = j0 + wn * 32 + n * 16 + cc;
        const float sfull = accS[m][n][jj];
        const float num   = accN[m][n][jj];
        const float nd    = accD[m][n][jj];
        const float nij   = sqrtf(fmaxf(nd, 0.f));
        const float sim   = num / (ni * fmaxf(nij, 1e-12f));
        const float d     = fabsf(sfull - sim);
        if (gi != gj) sum += d;
      }
    }
  }
  for (int off = 32; off > 0; off >>= 1) sum += __shfl_down(sum, off);
  if (lane == 0) red[wv] = sum;
  __syncthreads();
  if (t == 0) {
    float bs = 0.f;
    for (int w = 0; w < 8; ++w) bs += red[w];
    const float scale = 1.0f / (8192.0f * 8191.0f);
    atomicAdd(out, bs * scale);
  }
}

extern "C" void kernel_launch(void* const* d_in, const int* in_sizes, int n_in,
                              void* d_out, int out_size, void* d_ws, size_t ws_size,
                              hipStream_t stream) {
  const float* f    = (const float*)d_in[0];   // full_emb [8192,768] fp32
  const float* mask = (const float*)d_in[1];   // query_mask [8192,768] fp32
  float* out = (float*)d_out;                  // scalar loss
  float* n_i = (float*)d_ws;                   // 8192 floats of workspace

  rownorm_zero_kernel<<<B_ROWS / 4, 256, 0, stream>>>(f, mask, n_i, out);
  dim3 grid(B_ROWS / BN, B_ROWS / BM);
  fused_loss_kernel<<<grid, NTHREADS, 0, stream>>>(f, mask, n_i, out);
}

// Round 2
// 552.288 us; speedup vs baseline: 1.6334x; 1.6334x over previous
//
#include <hip/hip_runtime.h>
#include <hip/hip_bf16.h>

// Problem constants (fixed by reference setup_inputs)
#define B_ROWS 8192
#define D_DIM  768

// Tile config: 128x128 block tile, K-step 32, 512 threads = 8 waves (2x4),
// each wave owns a 64x32 output sub-tile = 4x2 fragments of 16x16.
#define BM 128
#define BN 128
#define BK 32
#define NTHREADS 512
#define KTILES (D_DIM / BK)            // 24
#define RTILES (B_ROWS / BM)           // 64
#define TILE_ELEMS (BM * BK)           // 4096 elems = 8192 B per panel-tile
#define PANEL_ELEMS ((size_t)B_ROWS * (size_t)D_DIM)   // 6291456
#define PANEL_BYTES (PANEL_ELEMS * 2)                  // 12582912 B

typedef __attribute__((ext_vector_type(8))) short bf16x8;           // MFMA A/B frag (8 bf16)
typedef __attribute__((ext_vector_type(8))) unsigned short u16x8;   // 16B vector store
typedef __attribute__((ext_vector_type(4))) float f32x4;            // MFMA C/D frag

__device__ __forceinline__ unsigned short f2bf(float x) {
  // round-to-nearest-even fp32 -> bf16 (inputs are finite; no NaN handling)
  unsigned int u = __float_as_uint(x);
  u += 0x7fffu + ((u >> 16) & 1u);
  return (unsigned short)(u >> 16);
}

__device__ __forceinline__ float4 f4mul(float4 a, float4 b) {
  return make_float4(a.x * b.x, a.y * b.y, a.z * b.z, a.w * b.w);
}

__device__ __forceinline__ u16x8 cvt8(float4 a, float4 b) {
  u16x8 v;
  v[0] = f2bf(a.x); v[1] = f2bf(a.y); v[2] = f2bf(a.z); v[3] = f2bf(a.w);
  v[4] = f2bf(b.x); v[5] = f2bf(b.y); v[6] = f2bf(b.z); v[7] = f2bf(b.w);
  return v;
}

// Direct global->LDS async copy, 16B per lane. LDS dest must be
// wave-uniform-base + lane*16 (guaranteed by te = tid*8 elems mapping).
// AS casts via inttoptr (CK pattern): low 32 bits of a generic LDS pointer
// are the LDS offset on gfx9xx.
__device__ __forceinline__ void gload16(const void* g, void* l) {
  __builtin_amdgcn_global_load_lds(
      (const __attribute__((address_space(1))) unsigned int*)(uintptr_t)g,
      (__attribute__((address_space(3))) unsigned int*)(unsigned int)(uintptr_t)l,
      16, 0, 0);
}

// Kernel 1: n_i = max(||f_i * m_i||, eps) in fp32; also zero the output scalar.
__global__ __launch_bounds__(256) void rownorm_zero_kernel(
    const float* __restrict__ f, const float* __restrict__ mask,
    float* __restrict__ n_i, float* __restrict__ out) {
  if (blockIdx.x == 0 && threadIdx.x == 0) out[0] = 0.0f;
  const int wv = threadIdx.x >> 6;
  const int lane = threadIdx.x & 63;
  const int row = blockIdx.x * 4 + wv;
  const float* fr = f + (size_t)row * D_DIM;
  const float* mr = mask + (size_t)row * D_DIM;
  float s = 0.f;
  for (int d = lane; d < D_DIM; d += 64) {
    float v = fr[d] * mr[d];
    s += v * v;
  }
  for (int off = 32; off > 0; off >>= 1) s += __shfl_down(s, off);
  if (lane == 0) n_i[row] = fmaxf(sqrtf(s), 1e-12f);
}

// Kernel 2 (pre-pass): convert fp32 inputs into four bf16 operand panels in
// d_ws, in a tiled layout: panel[tr][tk][128][32] with an XOR chunk-swizzle
// within each row (chunk' = chunk ^ ((row>>1)&3), chunks of 8 elems = 16B).
// This makes main-kernel staging LINEAR (global_load_lds legal) and the
// ds_read_b128 fragment reads ~conflict-free (8 bank-quads per 8 rows).
__global__ __launch_bounds__(256) void convert_kernel(
    const float* __restrict__ f, const float* __restrict__ mask,
    unsigned short* __restrict__ pF, unsigned short* __restrict__ pFM2,
    unsigned short* __restrict__ pM2, unsigned short* __restrict__ pF2) {
  const int g = blockIdx.x * 256 + threadIdx.x;   // 8192*96 units of 8 elems
  const int r = g / (D_DIM / 8);
  const int chunk = g - r * (D_DIM / 8);          // 0..95
  const float* fr = f + (size_t)r * D_DIM + chunk * 8;
  const float* mr = mask + (size_t)r * D_DIM + chunk * 8;
  float4 fv0 = *(const float4*)(fr);
  float4 fv1 = *(const float4*)(fr + 4);
  float4 mv0 = *(const float4*)(mr);
  float4 mv1 = *(const float4*)(mr + 4);
  float4 m20 = f4mul(mv0, mv0), m21 = f4mul(mv1, mv1);
  float4 fm0 = f4mul(fv0, m20), fm1 = f4mul(fv1, m21);
  float4 f20 = f4mul(fv0, fv0), f21 = f4mul(fv1, fv1);

  const int tr = r >> 7, rr = r & 127;
  const int tk = chunk >> 2, ch = chunk & 3;
  const int sc = (ch ^ ((rr >> 1) & 3)) << 3;     // swizzled elem col
  const size_t off = ((size_t)(tr * KTILES + tk)) * TILE_ELEMS + rr * 32 + sc;
  *(u16x8*)(pF + off)   = cvt8(fv0, fv1);
  *(u16x8*)(pFM2 + off) = cvt8(fm0, fm1);
  *(u16x8*)(pM2 + off)  = cvt8(m20, m21);
  *(u16x8*)(pF2 + off)  = cvt8(f20, f21);
}

// Kernel 3: fused triple-GEMM + pointwise loss + reduction, bf16 panels in,
// global_load_lds staging, m97-style 2-barrier loop.
//  accS = f_i . f_j          (teacher sim)
//  accN = (f_i*m2_i) . f_j   (student numerator)
//  accD = m2_i . f_j^2       (student denom^2 term)
__global__ __launch_bounds__(NTHREADS) void fused_loss_bf16_kernel(
    const unsigned short* __restrict__ pF, const unsigned short* __restrict__ pFM2,
    const unsigned short* __restrict__ pM2, const unsigned short* __restrict__ pF2,
    const float* __restrict__ n_i, float* __restrict__ out) {
  __shared__ unsigned short sF[TILE_ELEMS];
  __shared__ unsigned short sFM2[TILE_ELEMS];
  __shared__ unsigned short sM2[TILE_ELEMS];
  __shared__ unsigned short sBF[TILE_ELEMS];
  __shared__ unsigned short sBF2[TILE_ELEMS];
  __shared__ float red[8];

  const int t    = threadIdx.x;
  const int lane = t & 63;
  const int wv   = t >> 6;        // wave id 0..7
  const int wm   = wv >> 2;       // 0..1  (row group of 64)
  const int wn   = wv & 3;        // 0..3  (col group of 32)
  const int frg  = lane & 15;     // fragment row
  const int ch   = lane >> 4;     // fragment k-chunk (8 bf16 = 16B)

  const int trA = blockIdx.y;     // i0 = trA*128
  const int trB = blockIdx.x;     // j0 = trB*128
  const size_t baseA = (size_t)trA * KTILES * TILE_ELEMS;
  const size_t baseB = (size_t)trB * KTILES * TILE_ELEMS;
  const int te = t * 8;           // staging: elem offset, 16B per thread

  // Precompute swizzled ds_read element offsets (fixed per thread).
  int offA[4], offB[2];
#pragma unroll
  for (int m = 0; m < 4; ++m) {
    const int rr = wm * 64 + m * 16 + frg;
    offA[m] = rr * 32 + ((ch ^ ((rr >> 1) & 3)) << 3);
  }
#pragma unroll
  for (int n = 0; n < 2; ++n) {
    const int rr = wn * 32 + n * 16 + frg;
    offB[n] = rr * 32 + ((ch ^ ((rr >> 1) & 3)) << 3);
  }

  f32x4 accS[4][2], accN[4][2], accD[4][2];
#pragma unroll
  for (int m = 0; m < 4; ++m)
#pragma unroll
    for (int n = 0; n < 2; ++n) {
      accS[m][n] = {0.f, 0.f, 0.f, 0.f};
      accN[m][n] = {0.f, 0.f, 0.f, 0.f};
      accD[m][n] = {0.f, 0.f, 0.f, 0.f};
    }

  for (int tk = 0; tk < KTILES; ++tk) {
    __syncthreads();  // readers of previous tile done
    const size_t toff = (size_t)tk * TILE_ELEMS + te;
    gload16(pF   + baseA + toff, sF + te);
    gload16(pFM2 + baseA + toff, sFM2 + te);
    gload16(pM2  + baseA + toff, sM2 + te);
    gload16(pF   + baseB + toff, sBF + te);
    gload16(pF2  + baseB + toff, sBF2 + te);
    asm volatile("s_waitcnt vmcnt(0)" ::: "memory");
    __syncthreads();

    bf16x8 bF[2], bF2[2];
#pragma unroll
    for (int n = 0; n < 2; ++n) {
      bF[n]  = *(const bf16x8*)(sBF + offB[n]);
      bF2[n] = *(const bf16x8*)(sBF2 + offB[n]);
    }
#pragma unroll
    for (int m = 0; m < 4; ++m) {
      bf16x8 aF = *(const bf16x8*)(sF + offA[m]);
      bf16x8 aN = *(const bf16x8*)(sFM2 + offA[m]);
      bf16x8 aD = *(const bf16x8*)(sM2 + offA[m]);
#pragma unroll
      for (int n = 0; n < 2; ++n) {
        accS[m][n] = __builtin_amdgcn_mfma_f32_16x16x32_bf16(aF, bF[n],  accS[m][n], 0, 0, 0);
        accN[m][n] = __builtin_amdgcn_mfma_f32_16x16x32_bf16(aN, bF[n],  accN[m][n], 0, 0, 0);
        accD[m][n] = __builtin_amdgcn_mfma_f32_16x16x32_bf16(aD, bF2[n], accD[m][n], 0, 0, 0);
      }
    }
  }

  // ---- epilogue: pointwise loss + off-diagonal masked reduction ----
  // C/D layout (m89-verified): col = lane&15, row = (lane>>4)*4 + reg
  float sum = 0.f;
  const int r4 = (lane >> 4) * 4;
  const int cc = lane & 15;
  const int i0 = trA * BM;
  const int j0 = trB * BN;
#pragma unroll
  for (int m = 0; m < 4; ++m) {
    const int gi_base = i0 + wm * 64 + m * 16 + r4;
#pragma unroll
    for (int jj = 0; jj < 4; ++jj) {
      const int gi = gi_base + jj;
      const float ni = n_i[gi];
#pragma unroll
      for (int n = 0; n < 2; ++n) {
        const int gj = j0 + wn * 32 + n * 16 + cc;
        const float sfull = accS[m][n][jj];
        const float num   = accN[m][n][jj];
        const float nd    = accD[m][n][jj];
        const float nij   = sqrtf(fmaxf(nd, 0.f));
        const float sim   = num / (ni * fmaxf(nij, 1e-12f));
        const float d     = fabsf(sfull - sim);
        if (gi != gj) sum += d;
      }
    }
  }
  for (int off = 32; off > 0; off >>= 1) sum += __shfl_down(sum, off);
  if (lane == 0) red[wv] = sum;
  __syncthreads();
  if (t == 0) {
    float bs = 0.f;
    for (int w = 0; w < 8; ++w) bs += red[w];
    const float scale = 1.0f / (8192.0f * 8191.0f);
    atomicAdd(out, bs * scale);
  }
}

// ---------------- Fallback path (ws too small): round-1 kernel ----------------
__global__ __launch_bounds__(NTHREADS, 2) void fused_loss_kernel(
    const float* __restrict__ f, const float* __restrict__ mask,
    const float* __restrict__ n_i, float* __restrict__ out) {
  __shared__ unsigned short sF[BM][BK];
  __shared__ unsigned short sFM2[BM][BK];
  __shared__ unsigned short sM2[BM][BK];
  __shared__ unsigned short sBF[BN][BK];
  __shared__ unsigned short sBF2[BN][BK];
  __shared__ float red[8];

  const int t    = threadIdx.x;
  const int lane = t & 63;
  const int wv   = t >> 6;
  const int wm   = wv >> 2;
  const int wn   = wv & 3;
  const int frg  = lane & 15;
  const int ko   = (lane >> 4) * 8;

  const int i0 = blockIdx.y * BM;
  const int j0 = blockIdx.x * BN;
  const int ar = t >> 2;
  const int ac = (t & 3) * 8;

  f32x4 accS[4][2], accN[4][2], accD[4][2];
  for (int m = 0; m < 4; ++m)
    for (int n = 0; n < 2; ++n) {
      accS[m][n] = {0.f, 0.f, 0.f, 0.f};
      accN[m][n] = {0.f, 0.f, 0.f, 0.f};
      accD[m][n] = {0.f, 0.f, 0.f, 0.f};
    }

  const float* fA = f    + (size_t)(i0 + ar) * D_DIM + ac;
  const float* mA = mask + (size_t)(i0 + ar) * D_DIM + ac;
  const float* fB = f    + (size_t)(j0 + ar) * D_DIM + ac;

  for (int k0 = 0; k0 < D_DIM; k0 += BK) {
    __syncthreads();
    float4 fa0 = *(const float4*)(fA + k0);
    float4 fa1 = *(const float4*)(fA + k0 + 4);
    float4 ma0 = *(const float4*)(mA + k0);
    float4 ma1 = *(const float4*)(mA + k0 + 4);
    float4 fb0 = *(const float4*)(fB + k0);
    float4 fb1 = *(const float4*)(fB + k0 + 4);
    float4 m20 = f4mul(ma0, ma0), m21 = f4mul(ma1, ma1);
    float4 fm0 = f4mul(fa0, m20), fm1 = f4mul(fa1, m21);
    float4 f20 = f4mul(fb0, fb0), f21 = f4mul(fb1, fb1);
    *(u16x8*)&sF[ar][ac]   = cvt8(fa0, fa1);
    *(u16x8*)&sFM2[ar][ac] = cvt8(fm0, fm1);
    *(u16x8*)&sM2[ar][ac]  = cvt8(m20, m21);
    *(u16x8*)&sBF[ar][ac]  = cvt8(fb0, fb1);
    *(u16x8*)&sBF2[ar][ac] = cvt8(f20, f21);
    __syncthreads();
    bf16x8 bF[2], bF2[2];
    for (int n = 0; n < 2; ++n) {
      bF[n]  = *(const bf16x8*)&sBF [wn * 32 + n * 16 + frg][ko];
      bF2[n] = *(const bf16x8*)&sBF2[wn * 32 + n * 16 + frg][ko];
    }
#pragma unroll
    for (int m = 0; m < 4; ++m) {
      bf16x8 aF = *(const bf16x8*)&sF  [wm * 64 + m * 16 + frg][ko];
      bf16x8 aN = *(const bf16x8*)&sFM2[wm * 64 + m * 16 + frg][ko];
      bf16x8 aD = *(const bf16x8*)&sM2 [wm * 64 + m * 16 + frg][ko];
#pragma unroll
      for (int n = 0; n < 2; ++n) {
        accS[m][n] = __builtin_amdgcn_mfma_f32_16x16x32_bf16(aF, bF[n],  accS[m][n], 0, 0, 0);
        accN[m][n] = __builtin_amdgcn_mfma_f32_16x16x32_bf16(aN, bF[n],  accN[m][n], 0, 0, 0);
        accD[m][n] = __builtin_amdgcn_mfma_f32_16x16x32_bf16(aD, bF2[n], accD[m][n], 0, 0, 0);
      }
    }
  }

  float sum = 0.f;
  const int r4 = (lane >> 4) * 4;
  const int cc = lane & 15;
#pragma unroll
  for (int m = 0; m < 4; ++m) {
    const int gi_base = i0 + wm * 64 + m * 16 + r4;
#pragma unroll
    for (int jj = 0; jj < 4; ++jj) {
      const int gi = gi_base + jj;
      const float ni = n_i[gi];
#pragma unroll
      for (int n = 0; n < 2; ++n) {
        const int gj = j0 + wn * 32 + n * 16 + cc;
        const float sfull = accS[m][n][jj];
        const float num   = accN[m][n][jj];
        const float nd    = accD[m][n][jj];
        const float nij   = sqrtf(fmaxf(nd, 0.f));
        const float sim   = num / (ni * fmaxf(nij, 1e-12f));
        const float d     = fabsf(sfull - sim);
        if (gi != gj) sum += d;
      }
    }
  }
  for (int off = 32; off > 0; off >>= 1) sum += __shfl_down(sum, off);
  if (lane == 0) red[wv] = sum;
  __syncthreads();
  if (t == 0) {
    float bs = 0.f;
    for (int w = 0; w < 8; ++w) bs += red[w];
    const float scale = 1.0f / (8192.0f * 8191.0f);
    atomicAdd(out, bs * scale);
  }
}

extern "C" void kernel_launch(void* const* d_in, const int* in_sizes, int n_in,
                              void* d_out, int out_size, void* d_ws, size_t ws_size,
                              hipStream_t stream) {
  const float* f    = (const float*)d_in[0];   // full_emb [8192,768] fp32
  const float* mask = (const float*)d_in[1];   // query_mask [8192,768] fp32
  float* out = (float*)d_out;                  // scalar loss

  const size_t need = 4 * PANEL_BYTES + (size_t)B_ROWS * sizeof(float);
  if (ws_size >= need) {
    unsigned short* pF   = (unsigned short*)d_ws;
    unsigned short* pFM2 = pF + PANEL_ELEMS;
    unsigned short* pM2  = pFM2 + PANEL_ELEMS;
    unsigned short* pF2  = pM2 + PANEL_ELEMS;
    float* n_i = (float*)(pF2 + PANEL_ELEMS);
    rownorm_zero_kernel<<<B_ROWS / 4, 256, 0, stream>>>(f, mask, n_i, out);
    convert_kernel<<<(B_ROWS * (D_DIM / 8)) / 256, 256, 0, stream>>>(
        f, mask, pF, pFM2, pM2, pF2);
    dim3 grid(RTILES, RTILES);
    fused_loss_bf16_kernel<<<grid, NTHREADS, 0, stream>>>(pF, pFM2, pM2, pF2, n_i, out);
  } else {
    float* n_i = (float*)d_ws;
    rownorm_zero_kernel<<<B_ROWS / 4, 256, 0, stream>>>(f, mask, n_i, out);
    dim3 grid(B_ROWS / BN, B_ROWS / BM);
    fused_loss_kernel<<<grid, NTHREADS, 0, stream>>>(f, mask, n_i, out);
  }
}

// Round 3
// 357.692 us; speedup vs baseline: 2.5220x; 1.5440x over previous
//
#include <hip/hip_runtime.h>
#include <hip/hip_bf16.h>

// Problem constants (fixed by reference setup_inputs)
#define B_ROWS 8192
#define D_DIM  768

// Main-kernel tile config: 128(I) x 256(J) block tile, K-step 32,
// 512 threads = 8 waves (2 wm x 4 wn), each wave owns a 64x64 output tile
// = 4x4 fragments of 16x16 per GEMM (3 GEMMs -> 48 f32x4 accumulators).
#define BI 128
#define BJ 256
#define BK 32
#define NTHREADS 512
#define KTILES (D_DIM / BK)            // 24
#define RTILES (B_ROWS / 128)          // 64 row-tiles of 128 (panel layout)
#define TILE_ELEMS (128 * BK)          // 4096 elems = 8192 B per panel-tile
#define PANEL_ELEMS ((size_t)B_ROWS * (size_t)D_DIM)   // 6291456
#define PANEL_BYTES (PANEL_ELEMS * 2)                  // 12582912 B

// LDS buffer layout (elems): sF@0(4096) sFM2@4096 sM2@8192 sBF@12288(8192) sBF2@20480(8192)
#define LDS_F    0
#define LDS_FM2  4096
#define LDS_M2   8192
#define LDS_BF   12288
#define LDS_BF2  20480
#define LDSBUF_ELEMS 28672             // 57344 B per buffer; x2 = 114688 B

typedef __attribute__((ext_vector_type(8))) short bf16x8;           // MFMA A/B frag (8 bf16)
typedef __attribute__((ext_vector_type(8))) unsigned short u16x8;   // 16B vector store
typedef __attribute__((ext_vector_type(4))) float f32x4;            // MFMA C/D frag

__device__ __forceinline__ unsigned short f2bf(float x) {
  unsigned int u = __float_as_uint(x);
  u += 0x7fffu + ((u >> 16) & 1u);
  return (unsigned short)(u >> 16);
}

__device__ __forceinline__ float4 f4mul(float4 a, float4 b) {
  return make_float4(a.x * b.x, a.y * b.y, a.z * b.z, a.w * b.w);
}

__device__ __forceinline__ u16x8 cvt8(float4 a, float4 b) {
  u16x8 v;
  v[0] = f2bf(a.x); v[1] = f2bf(a.y); v[2] = f2bf(a.z); v[3] = f2bf(a.w);
  v[4] = f2bf(b.x); v[5] = f2bf(b.y); v[6] = f2bf(b.z); v[7] = f2bf(b.w);
  return v;
}

// Direct global->LDS async copy, 16B per lane (wave-uniform LDS base + lane*16).
__device__ __forceinline__ void gload16(const void* g, void* l) {
  __builtin_amdgcn_global_load_lds(
      (const __attribute__((address_space(1))) unsigned int*)(uintptr_t)g,
      (__attribute__((address_space(3))) unsigned int*)(unsigned int)(uintptr_t)l,
      16, 0, 0);
}

// Kernel 1: rn_i = 1 / max(||f_i * m_i||, eps) (reciprocal!); zero out scalar.
__global__ __launch_bounds__(256) void rownorm_zero_kernel(
    const float* __restrict__ f, const float* __restrict__ mask,
    float* __restrict__ rn_i, float* __restrict__ out) {
  if (blockIdx.x == 0 && threadIdx.x == 0) out[0] = 0.0f;
  const int wv = threadIdx.x >> 6;
  const int lane = threadIdx.x & 63;
  const int row = blockIdx.x * 4 + wv;
  const float* fr = f + (size_t)row * D_DIM;
  const float* mr = mask + (size_t)row * D_DIM;
  float s = 0.f;
  for (int d = lane; d < D_DIM; d += 64) {
    float v = fr[d] * mr[d];
    s += v * v;
  }
  for (int off = 32; off > 0; off >>= 1) s += __shfl_down(s, off);
  if (lane == 0) rn_i[row] = 1.0f / fmaxf(sqrtf(s), 1e-12f);
}

// Kernel 2 (pre-pass): fp32 inputs -> four bf16 operand panels, tiled
// panel[tr][tk][128][32] with XOR chunk-swizzle (chunk' = chunk ^ ((row>>1)&3),
// 8-elem chunks). Main kernel stages LINEARLY (global_load_lds) and reads with
// the matching swizzle -> measured 0 bank conflicts (R2).
__global__ __launch_bounds__(256) void convert_kernel(
    const float* __restrict__ f, const float* __restrict__ mask,
    unsigned short* __restrict__ pF, unsigned short* __restrict__ pFM2,
    unsigned short* __restrict__ pM2, unsigned short* __restrict__ pF2) {
  const int g = blockIdx.x * 256 + threadIdx.x;   // 8192*96 chunks of 8 elems
  const int r = g / (D_DIM / 8);
  const int chunk = g - r * (D_DIM / 8);          // 0..95
  const float* fr = f + (size_t)r * D_DIM + chunk * 8;
  const float* mr = mask + (size_t)r * D_DIM + chunk * 8;
  float4 fv0 = *(const float4*)(fr);
  float4 fv1 = *(const float4*)(fr + 4);
  float4 mv0 = *(const float4*)(mr);
  float4 mv1 = *(const float4*)(mr + 4);
  float4 m20 = f4mul(mv0, mv0), m21 = f4mul(mv1, mv1);
  float4 fm0 = f4mul(fv0, m20), fm1 = f4mul(fv1, m21);
  float4 f20 = f4mul(fv0, fv0), f21 = f4mul(fv1, fv1);

  const int tr = r >> 7, rr = r & 127;
  const int tk = chunk >> 2, ch = chunk & 3;
  const int sc = (ch ^ ((rr >> 1) & 3)) << 3;     // swizzled elem col
  const size_t off = ((size_t)(tr * KTILES + tk)) * TILE_ELEMS + rr * 32 + sc;
  *(u16x8*)(pF + off)   = cvt8(fv0, fv1);
  *(u16x8*)(pFM2 + off) = cvt8(fm0, fm1);
  *(u16x8*)(pM2 + off)  = cvt8(m20, m21);
  *(u16x8*)(pF2 + off)  = cvt8(f20, f21);
}

// Kernel 3: fused triple-GEMM + loss. 128x256 tile, dbuf LDS, prefetch-before-
// compute with ONE vmcnt(0)+barrier per K-step (drain lands post-compute).
//  accS = f_i . f_j ; accN = (f_i*m2_i) . f_j ; accD = m2_i . f_j^2
__global__ __launch_bounds__(NTHREADS) void fused_loss_bf16_kernel(
    const unsigned short* __restrict__ pF, const unsigned short* __restrict__ pFM2,
    const unsigned short* __restrict__ pM2, const unsigned short* __restrict__ pF2,
    const float* __restrict__ rn_i, float* __restrict__ out) {
  __shared__ unsigned short lds[2 * LDSBUF_ELEMS];
  __shared__ float red[8];

  const int t    = threadIdx.x;
  const int lane = t & 63;
  const int wv   = t >> 6;        // wave id 0..7
  const int wm   = wv >> 2;       // 0..1  (row group of 64)
  const int wn   = wv & 3;        // 0..3  (col group of 64)
  const int frg  = lane & 15;     // fragment row
  const int ch   = lane >> 4;     // fragment k-chunk (8 bf16 = 16B)

  const int trA = blockIdx.y;     // i0 = trA*128
  const int trB = blockIdx.x;     // j0 = trB*256 -> panel row-tiles 2trB, 2trB+1
  const int te  = t * 8;          // staging elem offset (16B per thread)

  const size_t baseA  = (size_t)(trA * KTILES) * TILE_ELEMS;
  const size_t baseB0 = (size_t)((2 * trB) * KTILES) * TILE_ELEMS;
  const size_t baseB1 = (size_t)((2 * trB + 1) * KTILES) * TILE_ELEMS;

  // Precomputed swizzled ds_read elem offsets (fixed per thread).
  int offA[4], offB[4];
#pragma unroll
  for (int m = 0; m < 4; ++m) {
    const int rr = wm * 64 + m * 16 + frg;            // 0..127
    offA[m] = rr * 32 + ((ch ^ ((rr >> 1) & 3)) << 3);
  }
#pragma unroll
  for (int n = 0; n < 4; ++n) {
    const int rB = wn * 64 + n * 16 + frg;            // 0..255
    const int rt = rB >> 7, rr = rB & 127;
    offB[n] = rt * TILE_ELEMS + rr * 32 + ((ch ^ ((rr >> 1) & 3)) << 3);
  }

  f32x4 accS[4][4], accN[4][4], accD[4][4];
#pragma unroll
  for (int m = 0; m < 4; ++m)
#pragma unroll
    for (int n = 0; n < 4; ++n) {
      accS[m][n] = {0.f, 0.f, 0.f, 0.f};
      accN[m][n] = {0.f, 0.f, 0.f, 0.f};
      accD[m][n] = {0.f, 0.f, 0.f, 0.f};
    }

#define STAGE(b, tk)                                                          \
  do {                                                                        \
    const size_t _tA  = baseA  + (size_t)(tk) * TILE_ELEMS + te;              \
    const size_t _tB0 = baseB0 + (size_t)(tk) * TILE_ELEMS + te;              \
    const size_t _tB1 = baseB1 + (size_t)(tk) * TILE_ELEMS + te;              \
    gload16(pF   + _tA,  (b) + LDS_F   + te);                                 \
    gload16(pFM2 + _tA,  (b) + LDS_FM2 + te);                                 \
    gload16(pM2  + _tA,  (b) + LDS_M2  + te);                                 \
    gload16(pF   + _tB0, (b) + LDS_BF  + te);                                 \
    gload16(pF   + _tB1, (b) + LDS_BF  + TILE_ELEMS + te);                    \
    gload16(pF2  + _tB0, (b) + LDS_BF2 + te);                                 \
    gload16(pF2  + _tB1, (b) + LDS_BF2 + TILE_ELEMS + te);                    \
  } while (0)

  unsigned short* const buf0 = lds;
  unsigned short* const buf1 = lds + LDSBUF_ELEMS;

  STAGE(buf0, 0);
  asm volatile("s_waitcnt vmcnt(0)" ::: "memory");
  __syncthreads();

  int cur = 0;
  for (int tk = 0; tk < KTILES; ++tk) {
    unsigned short* const cb = cur ? buf1 : buf0;
    unsigned short* const nb = cur ? buf0 : buf1;
    if (tk + 1 < KTILES) STAGE(nb, tk + 1);   // prefetch issued BEFORE compute

    bf16x8 bF[4], bF2[4];
#pragma unroll
    for (int n = 0; n < 4; ++n) {
      bF[n]  = *(const bf16x8*)(cb + LDS_BF  + offB[n]);
      bF2[n] = *(const bf16x8*)(cb + LDS_BF2 + offB[n]);
    }
#pragma unroll
    for (int m = 0; m < 4; ++m) {
      bf16x8 aF = *(const bf16x8*)(cb + LDS_F   + offA[m]);
      bf16x8 aN = *(const bf16x8*)(cb + LDS_FM2 + offA[m]);
      bf16x8 aD = *(const bf16x8*)(cb + LDS_M2  + offA[m]);
#pragma unroll
      for (int n = 0; n < 4; ++n) {
        accS[m][n] = __builtin_amdgcn_mfma_f32_16x16x32_bf16(aF, bF[n],  accS[m][n], 0, 0, 0);
        accN[m][n] = __builtin_amdgcn_mfma_f32_16x16x32_bf16(aN, bF[n],  accN[m][n], 0, 0, 0);
        accD[m][n] = __builtin_amdgcn_mfma_f32_16x16x32_bf16(aD, bF2[n], accD[m][n], 0, 0, 0);
      }
    }
    // Drain prefetch (issued one full compute-phase ago) then swap buffers.
    asm volatile("s_waitcnt vmcnt(0)" ::: "memory");
    __syncthreads();
    cur ^= 1;
  }
#undef STAGE

  // ---- epilogue: pointwise loss + off-diagonal masked reduction ----
  // C/D layout (m89-verified): col = lane&15, row = (lane>>4)*4 + reg
  float sum = 0.f;
  const int r4 = (lane >> 4) * 4;
  const int cc = lane & 15;
  const int i0 = trA * BI;
  const int j0 = trB * BJ;
#pragma unroll
  for (int m = 0; m < 4; ++m) {
    const int gi_base = i0 + wm * 64 + m * 16 + r4;
#pragma unroll
    for (int jj = 0; jj < 4; ++jj) {
      const int gi = gi_base + jj;
      const float rni = rn_i[gi];
#pragma unroll
      for (int n = 0; n < 4; ++n) {
        const int gj = j0 + wn * 64 + n * 16 + cc;
        const float sfull = accS[m][n][jj];
        const float num   = accN[m][n][jj];
        const float nd    = accD[m][n][jj];
        // 1/max(sqrt(nd),1e-12) == rsqrt(max(nd,1e-24))
        const float rnij  = rsqrtf(fmaxf(nd, 1e-24f));
        const float sim   = num * rni * rnij;
        const float d     = fabsf(sfull - sim);
        if (gi != gj) sum += d;
      }
    }
  }
  for (int off = 32; off > 0; off >>= 1) sum += __shfl_down(sum, off);
  if (lane == 0) red[wv] = sum;
  __syncthreads();
  if (t == 0) {
    float bs = 0.f;
    for (int w = 0; w < 8; ++w) bs += red[w];
    const float scale = 1.0f / (8192.0f * 8191.0f);
    atomicAdd(out, bs * scale);
  }
}

// ---------------- Fallback path (ws too small): round-1 kernel ----------------
__global__ __launch_bounds__(NTHREADS, 2) void fused_loss_kernel(
    const float* __restrict__ f, const float* __restrict__ mask,
    const float* __restrict__ rn_i, float* __restrict__ out) {
  __shared__ unsigned short sF[128][BK];
  __shared__ unsigned short sFM2[128][BK];
  __shared__ unsigned short sM2[128][BK];
  __shared__ unsigned short sBF[128][BK];
  __shared__ unsigned short sBF2[128][BK];
  __shared__ float red[8];

  const int t    = threadIdx.x;
  const int lane = t & 63;
  const int wv   = t >> 6;
  const int wm   = wv >> 2;
  const int wn   = wv & 3;
  const int frg  = lane & 15;
  const int ko   = (lane >> 4) * 8;

  const int i0 = blockIdx.y * 128;
  const int j0 = blockIdx.x * 128;
  const int ar = t >> 2;
  const int ac = (t & 3) * 8;

  f32x4 accS[4][2], accN[4][2], accD[4][2];
  for (int m = 0; m < 4; ++m)
    for (int n = 0; n < 2; ++n) {
      accS[m][n] = {0.f, 0.f, 0.f, 0.f};
      accN[m][n] = {0.f, 0.f, 0.f, 0.f};
      accD[m][n] = {0.f, 0.f, 0.f, 0.f};
    }

  const float* fA = f    + (size_t)(i0 + ar) * D_DIM + ac;
  const float* mA = mask + (size_t)(i0 + ar) * D_DIM + ac;
  const float* fB = f    + (size_t)(j0 + ar) * D_DIM + ac;

  for (int k0 = 0; k0 < D_DIM; k0 += BK) {
    __syncthreads();
    float4 fa0 = *(const float4*)(fA + k0);
    float4 fa1 = *(const float4*)(fA + k0 + 4);
    float4 ma0 = *(const float4*)(mA + k0);
    float4 ma1 = *(const float4*)(mA + k0 + 4);
    float4 fb0 = *(const float4*)(fB + k0);
    float4 fb1 = *(const float4*)(fB + k0 + 4);
    float4 m20 = f4mul(ma0, ma0), m21 = f4mul(ma1, ma1);
    float4 fm0 = f4mul(fa0, m20), fm1 = f4mul(fa1, m21);
    float4 f20 = f4mul(fb0, fb0), f21 = f4mul(fb1, fb1);
    *(u16x8*)&sF[ar][ac]   = cvt8(fa0, fa1);
    *(u16x8*)&sFM2[ar][ac] = cvt8(fm0, fm1);
    *(u16x8*)&sM2[ar][ac]  = cvt8(m20, m21);
    *(u16x8*)&sBF[ar][ac]  = cvt8(fb0, fb1);
    *(u16x8*)&sBF2[ar][ac] = cvt8(f20, f21);
    __syncthreads();
    bf16x8 bF[2], bF2[2];
    for (int n = 0; n < 2; ++n) {
      bF[n]  = *(const bf16x8*)&sBF [wn * 32 + n * 16 + frg][ko];
      bF2[n] = *(const bf16x8*)&sBF2[wn * 32 + n * 16 + frg][ko];
    }
#pragma unroll
    for (int m = 0; m < 4; ++m) {
      bf16x8 aF = *(const bf16x8*)&sF  [wm * 64 + m * 16 + frg][ko];
      bf16x8 aN = *(const bf16x8*)&sFM2[wm * 64 + m * 16 + frg][ko];
      bf16x8 aD = *(const bf16x8*)&sM2 [wm * 64 + m * 16 + frg][ko];
#pragma unroll
      for (int n = 0; n < 2; ++n) {
        accS[m][n] = __builtin_amdgcn_mfma_f32_16x16x32_bf16(aF, bF[n],  accS[m][n], 0, 0, 0);
        accN[m][n] = __builtin_amdgcn_mfma_f32_16x16x32_bf16(aN, bF[n],  accN[m][n], 0, 0, 0);
        accD[m][n] = __builtin_amdgcn_mfma_f32_16x16x32_bf16(aD, bF2[n], accD[m][n], 0, 0, 0);
      }
    }
  }

  float sum = 0.f;
  const int r4 = (lane >> 4) * 4;
  const int cc = lane & 15;
#pragma unroll
  for (int m = 0; m < 4; ++m) {
    const int gi_base = i0 + wm * 64 + m * 16 + r4;
#pragma unroll
    for (int jj = 0; jj < 4; ++jj) {
      const int gi = gi_base + jj;
      const float rni = rn_i[gi];
#pragma unroll
      for (int n = 0; n < 2; ++n) {
        const int gj = j0 + wn * 32 + n * 16 + cc;
        const float sfull = accS[m][n][jj];
        const float num   = accN[m][n][jj];
        const float nd    = accD[m][n][jj];
        const float rnij  = rsqrtf(fmaxf(nd, 1e-24f));
        const float sim   = num * rni * rnij;
        const float d     = fabsf(sfull - sim);
        if (gi != gj) sum += d;
      }
    }
  }
  for (int off = 32; off > 0; off >>= 1) sum += __shfl_down(sum, off);
  if (lane == 0) red[wv] = sum;
  __syncthreads();
  if (t == 0) {
    float bs = 0.f;
    for (int w = 0; w < 8; ++w) bs += red[w];
    const float scale = 1.0f / (8192.0f * 8191.0f);
    atomicAdd(out, bs * scale);
  }
}

extern "C" void kernel_launch(void* const* d_in, const int* in_sizes, int n_in,
                              void* d_out, int out_size, void* d_ws, size_t ws_size,
                              hipStream_t stream) {
  const float* f    = (const float*)d_in[0];   // full_emb [8192,768] fp32
  const float* mask = (const float*)d_in[1];   // query_mask [8192,768] fp32
  float* out = (float*)d_out;                  // scalar loss

  const size_t need = 4 * PANEL_BYTES + (size_t)B_ROWS * sizeof(float);
  if (ws_size >= need) {
    unsigned short* pF   = (unsigned short*)d_ws;
    unsigned short* pFM2 = pF + PANEL_ELEMS;
    unsigned short* pM2  = pFM2 + PANEL_ELEMS;
    unsigned short* pF2  = pM2 + PANEL_ELEMS;
    float* rn_i = (float*)(pF2 + PANEL_ELEMS);
    rownorm_zero_kernel<<<B_ROWS / 4, 256, 0, stream>>>(f, mask, rn_i, out);
    convert_kernel<<<(B_ROWS * (D_DIM / 8)) / 256, 256, 0, stream>>>(
        f, mask, pF, pFM2, pM2, pF2);
    dim3 grid(B_ROWS / BJ, B_ROWS / BI);   // 32 x 64
    fused_loss_bf16_kernel<<<grid, NTHREADS, 0, stream>>>(pF, pFM2, pM2, pF2, rn_i, out);
  } else {
    float* rn_i = (float*)d_ws;
    rownorm_zero_kernel<<<B_ROWS / 4, 256, 0, stream>>>(f, mask, rn_i, out);
    dim3 grid(B_ROWS / 128, B_ROWS / 128);
    fused_loss_kernel<<<grid, NTHREADS, 0, stream>>>(f, mask, rn_i, out);
  }
}